// Round 2
// baseline (580.745 us; speedup 1.0000x reference)
//
#include <hip/hip_runtime.h>
#include <math.h>

#define Nn 8192
#define Cc 256
#define Dd 128
#define CAP2 192   // max row degree: mean ~83, sigma ~9; max over 8192 rows ~120

// ---------------- h = x @ W^T ----------------
// 256 blocks x 256 threads; block handles 32 rows of x (LDS-staged).
// Thread owns d = tid&127 and 16 rows (g = tid>>7 picks which 16).
__global__ __launch_bounds__(256) void h_kernel(const float* __restrict__ x,
                                                const float* __restrict__ W,
                                                float* __restrict__ h) {
  __shared__ float xs[32 * Cc];  // 32 KB
  const int tid = threadIdx.x;
  const int row0 = blockIdx.x * 32;
  // stage 32 rows = 8192 floats = 2048 float4, coalesced
  const float4* xg4 = (const float4*)(x + (size_t)row0 * Cc);
  float4* xs4 = (float4*)xs;
#pragma unroll
  for (int k = 0; k < 8; ++k) xs4[tid + k * 256] = xg4[tid + k * 256];
  __syncthreads();

  const int d = tid & 127;
  const int g = tid >> 7;        // 0 or 1 -> rows [g*16, g*16+16)
  const float4* w4 = (const float4*)(W + (size_t)d * Cc);
  const float4* xt = (const float4*)(xs + g * 16 * Cc);

  float acc[16];
#pragma unroll
  for (int r = 0; r < 16; ++r) acc[r] = 0.f;

#pragma unroll 2
  for (int c4 = 0; c4 < Cc / 4; ++c4) {
    const float4 w = w4[c4];
#pragma unroll
    for (int r = 0; r < 16; ++r) {
      const float4 a = xt[r * (Cc / 4) + c4];  // wave-uniform LDS broadcast
      acc[r] += a.x * w.x + a.y * w.y + a.z * w.z + a.w * w.w;
    }
  }
  const int rbase = row0 + g * 16;
#pragma unroll
  for (int r = 0; r < 16; ++r) {
    h[(size_t)(rbase + r) * Dd + d] = acc[r];  // coalesced 512B per r
  }
}

// ---------------- graph row compaction (pure HBM stream) ----------------
// One block per row; 8 float4 per thread preloaded; ~1% of lanes take the
// atomic path. No barriers -> waves retire immediately, CU stays load-busy.
__global__ __launch_bounds__(256) void scan_kernel(const float* __restrict__ graph,
                                                   int* __restrict__ counts,
                                                   int* __restrict__ edges) {
  const int i = blockIdx.x;
  const int tid = threadIdx.x;
  const float4* row = (const float4*)(graph + (size_t)i * Nn);
  int* erow = edges + (size_t)i * CAP2;

  float4 v[8];
#pragma unroll
  for (int t = 0; t < 8; ++t) v[t] = row[t * 256 + tid];  // all 8 in flight

#pragma unroll
  for (int t = 0; t < 8; ++t) {
    const int c = 4 * (t * 256 + tid);
    if (v[t].x != 0.f) { int p = atomicAdd(&counts[i], 1); if (p < CAP2) erow[p] = c + 0; }
    if (v[t].y != 0.f) { int p = atomicAdd(&counts[i], 1); if (p < CAP2) erow[p] = c + 1; }
    if (v[t].z != 0.f) { int p = atomicAdd(&counts[i], 1); if (p < CAP2) erow[p] = c + 2; }
    if (v[t].w != 0.f) { int p = atomicAdd(&counts[i], 1); if (p < CAP2) erow[p] = c + 3; }
  }
}

// ---------------- sparse masked softmax + aggregate ----------------
// One block (128 threads = 2 waves) per row.
__global__ __launch_bounds__(128) void attn_kernel(const int* __restrict__ counts,
                                                   const int* __restrict__ edges,
                                                   const float* __restrict__ h,
                                                   const float* __restrict__ bias,
                                                   float* __restrict__ out) {
  __shared__ float hi[Dd];
  __shared__ int   idx[CAP2];
  __shared__ float sc[CAP2];
  __shared__ float redm[2];
  __shared__ float reds[2];
  const int i = blockIdx.x;
  const int tid = threadIdx.x;
  const int m = min(counts[i], CAP2);
  hi[tid] = h[(size_t)i * Dd + tid];
  __syncthreads();

  // scores: one edge per lane
  const float4* h4 = (const float4*)hi;
  const int* erow = edges + (size_t)i * CAP2;
  for (int e = tid; e < m; e += 128) {
    const int j = erow[e];
    idx[e] = j;
    const float4* hj = (const float4*)(h + (size_t)j * Dd);
    float s0 = 0.f, s1 = 0.f, s2 = 0.f, s3 = 0.f;
#pragma unroll
    for (int k = 0; k < Dd / 4; ++k) {
      const float4 a = h4[k];
      const float4 b = hj[k];
      s0 += a.x * b.x; s1 += a.y * b.y; s2 += a.z * b.z; s3 += a.w * b.w;
    }
    sc[e] = (s0 + s1) + (s2 + s3);
  }
  __syncthreads();

  // block max over unmasked (s != 0) scores
  float lmax = -INFINITY;
  for (int e = tid; e < m; e += 128) {
    const float s = sc[e];
    if (s != 0.f) lmax = fmaxf(lmax, s);
  }
#pragma unroll
  for (int off = 32; off > 0; off >>= 1) lmax = fmaxf(lmax, __shfl_down(lmax, off));
  const int lane = tid & 63, wv = tid >> 6;
  if (lane == 0) redm[wv] = lmax;
  __syncthreads();
  const float gmax = fmaxf(redm[0], redm[1]);

  // p = exp(s - max); block sum
  float lsum = 0.f;
  for (int e = tid; e < m; e += 128) {
    const float s = sc[e];
    const float p = (s != 0.f) ? __expf(s - gmax) : 0.f;
    sc[e] = p;
    lsum += p;
  }
#pragma unroll
  for (int off = 32; off > 0; off >>= 1) lsum += __shfl_down(lsum, off);
  if (lane == 0) reds[wv] = lsum;
  __syncthreads();
  const float inv = 1.f / (reds[0] + reds[1]);

  // out[i][d] = (sum_e p_e * h[j_e][d]) * inv + bias[d]; d = tid
  float acc = 0.f;
#pragma unroll 4
  for (int e = 0; e < m; ++e) {
    acc += sc[e] * h[(size_t)idx[e] * Dd + tid];  // coalesced 512B row reads
  }
  out[(size_t)i * Dd + tid] = acc * inv + bias[tid];
}

extern "C" void kernel_launch(void* const* d_in, const int* in_sizes, int n_in,
                              void* d_out, int out_size, void* d_ws, size_t ws_size,
                              hipStream_t stream) {
  const float* x     = (const float*)d_in[0];  // [1,8192,256]
  const float* graph = (const float*)d_in[1];  // [8192,8192]
  const float* W     = (const float*)d_in[2];  // [128,256]
  const float* bias  = (const float*)d_in[3];  // [128]
  float* out = (float*)d_out;                  // [1,8192,128]

  // workspace layout: h (4 MB) | counts (32 KB) | edges (6 MB)
  float* h      = (float*)d_ws;
  int*   counts = (int*)((char*)d_ws + (size_t)Nn * Dd * 4);
  int*   edges  = counts + Nn;

  hipMemsetAsync(counts, 0, Nn * sizeof(int), stream);
  h_kernel<<<Nn / 32, 256, 0, stream>>>(x, W, h);
  scan_kernel<<<Nn, 256, 0, stream>>>(graph, counts, edges);
  attn_kernel<<<Nn, 128, 0, stream>>>(counts, edges, h, bias, out);
}

// Round 4
// 550.225 us; speedup vs baseline: 1.0555x; 1.0555x over previous
//
#include <hip/hip_runtime.h>
#include <math.h>

#define Nn 8192
#define Cc 256
#define Dd 128
#define CAP 192   // max row degree: mean ~83, max over 8192 rows ~125

typedef float fx4 __attribute__((ext_vector_type(4)));  // nontemporal-load-able

// ---------------- h = x @ W^T ----------------
// 256 blocks x 256 threads; block handles 32 rows of x (LDS-staged).
__global__ __launch_bounds__(256) void h_kernel(const float* __restrict__ x,
                                                const float* __restrict__ W,
                                                float* __restrict__ h) {
  __shared__ float xs[32 * Cc];  // 32 KB
  const int tid = threadIdx.x;
  const int row0 = blockIdx.x * 32;
  const float4* xg4 = (const float4*)(x + (size_t)row0 * Cc);
  float4* xs4 = (float4*)xs;
#pragma unroll
  for (int k = 0; k < 8; ++k) xs4[tid + k * 256] = xg4[tid + k * 256];
  __syncthreads();

  const int d = tid & 127;
  const int g = tid >> 7;
  const float4* w4 = (const float4*)(W + (size_t)d * Cc);
  const float4* xt = (const float4*)(xs + g * 16 * Cc);

  float acc[16];
#pragma unroll
  for (int r = 0; r < 16; ++r) acc[r] = 0.f;

#pragma unroll 2
  for (int c4 = 0; c4 < Cc / 4; ++c4) {
    const float4 w = w4[c4];
#pragma unroll
    for (int r = 0; r < 16; ++r) {
      const float4 a = xt[r * (Cc / 4) + c4];  // wave-uniform LDS broadcast
      acc[r] += a.x * w.x + a.y * w.y + a.z * w.z + a.w * w.w;
    }
  }
  const int rbase = row0 + g * 16;
#pragma unroll
  for (int r = 0; r < 16; ++r) {
    h[(size_t)(rbase + r) * Dd + d] = acc[r];
  }
}

// ---------------- fused scan + sparse masked softmax + aggregate ----------
// ONE WAVE PER ROW. No barriers, no atomics. Ballot-compaction keeps the
// edge count in an SGPR; per-wave LDS slices hold idx/sc/hi.
__global__ __launch_bounds__(256, 4) void gat_wave(const float* __restrict__ graph,
                                                   const float* __restrict__ h,
                                                   const float* __restrict__ bias,
                                                   float* __restrict__ out) {
  __shared__ int   idxs[4][CAP];
  __shared__ float scs[4][CAP];
  __shared__ float his[4][Dd];
  const int wv   = threadIdx.x >> 6;
  const int lane = threadIdx.x & 63;
  const int i = blockIdx.x * 4 + wv;
  int*   idx = idxs[wv];
  float* sc  = scs[wv];
  float* hi  = his[wv];

  // stage h_i into this wave's LDS slice (wave-synchronous, no barrier)
  const float2 hiv = *(const float2*)(h + (size_t)i * Dd + lane * 2);
  *(float2*)(hi + lane * 2) = hiv;

  // ---- scan row i: chunked double-buffered nontemporal loads + ballot compact
  const fx4* row = (const fx4*)(graph + (size_t)i * Nn);
  const unsigned long long lmask = (1ull << lane) - 1ull;
  int cnt = 0;  // wave-uniform

  fx4 buf[4];
#pragma unroll
  for (int t = 0; t < 4; ++t) buf[t] = __builtin_nontemporal_load(&row[t * 64 + lane]);

#pragma unroll
  for (int c = 0; c < 8; ++c) {
    fx4 nbuf[4];
    if (c < 7) {
#pragma unroll
      for (int t = 0; t < 4; ++t)
        nbuf[t] = __builtin_nontemporal_load(&row[(c + 1) * 4 * 64 + t * 64 + lane]);
    }
#pragma unroll
    for (int t = 0; t < 4; ++t) {
      const fx4 v = buf[t];
      const int col = 4 * ((c * 4 + t) * 64 + lane);
      {
        const unsigned long long mk = __ballot(v.x != 0.f);
        if (v.x != 0.f) idx[cnt + __popcll(mk & lmask)] = col + 0;
        cnt += __popcll(mk);
      }
      {
        const unsigned long long mk = __ballot(v.y != 0.f);
        if (v.y != 0.f) idx[cnt + __popcll(mk & lmask)] = col + 1;
        cnt += __popcll(mk);
      }
      {
        const unsigned long long mk = __ballot(v.z != 0.f);
        if (v.z != 0.f) idx[cnt + __popcll(mk & lmask)] = col + 2;
        cnt += __popcll(mk);
      }
      {
        const unsigned long long mk = __ballot(v.w != 0.f);
        if (v.w != 0.f) idx[cnt + __popcll(mk & lmask)] = col + 3;
        cnt += __popcll(mk);
      }
    }
#pragma unroll
    for (int t = 0; t < 4; ++t) buf[t] = nbuf[t];
  }
  const int m = min(cnt, CAP);

  // ---- scores: one edge per lane (h is L2/L3-hot, 4 MB)
  const float4* h4 = (const float4*)hi;
  for (int e = lane; e < m; e += 64) {
    const int j = idx[e];
    const float4* hj = (const float4*)(h + (size_t)j * Dd);
    float s0 = 0.f, s1 = 0.f, s2 = 0.f, s3 = 0.f;
#pragma unroll
    for (int k = 0; k < Dd / 4; ++k) {
      const float4 a = h4[k];   // uniform LDS broadcast
      const float4 b = hj[k];
      s0 += a.x * b.x; s1 += a.y * b.y; s2 += a.z * b.z; s3 += a.w * b.w;
    }
    sc[e] = (s0 + s1) + (s2 + s3);
  }

  // ---- wave softmax over unmasked (s != 0) scores
  float lmax = -INFINITY;
  for (int e = lane; e < m; e += 64) {
    const float s = sc[e];
    if (s != 0.f) lmax = fmaxf(lmax, s);
  }
#pragma unroll
  for (int off = 32; off > 0; off >>= 1) lmax = fmaxf(lmax, __shfl_xor(lmax, off));

  float lsum = 0.f;
  for (int e = lane; e < m; e += 64) {
    const float s = sc[e];
    const float p = (s != 0.f) ? __expf(s - lmax) : 0.f;
    sc[e] = p;
    lsum += p;
  }
#pragma unroll
  for (int off = 32; off > 0; off >>= 1) lsum += __shfl_xor(lsum, off);
  const float inv = 1.f / lsum;

  // ---- aggregate: lane owns d = lane*2 .. +1 (coalesced 512B per edge)
  float accx = 0.f, accy = 0.f;
#pragma unroll 4
  for (int e = 0; e < m; ++e) {
    const float p = sc[e];        // uniform LDS broadcast
    const int j = idx[e];
    const float2 hv = *(const float2*)(h + (size_t)j * Dd + lane * 2);
    accx += p * hv.x;
    accy += p * hv.y;
  }
  const float2 bv = *(const float2*)(bias + lane * 2);
  float2 o;
  o.x = accx * inv + bv.x;
  o.y = accy * inv + bv.y;
  *(float2*)(out + (size_t)i * Dd + lane * 2) = o;
}

extern "C" void kernel_launch(void* const* d_in, const int* in_sizes, int n_in,
                              void* d_out, int out_size, void* d_ws, size_t ws_size,
                              hipStream_t stream) {
  const float* x     = (const float*)d_in[0];  // [1,8192,256]
  const float* graph = (const float*)d_in[1];  // [8192,8192]
  const float* W     = (const float*)d_in[2];  // [128,256]
  const float* bias  = (const float*)d_in[3];  // [128]
  float* out = (float*)d_out;                  // [1,8192,128]
  float* h = (float*)d_ws;                     // 4 MB scratch

  h_kernel<<<Nn / 32, 256, 0, stream>>>(x, W, h);
  gat_wave<<<Nn / 4, 256, 0, stream>>>(graph, h, bias, out);
}

// Round 5
// 485.430 us; speedup vs baseline: 1.1964x; 1.1335x over previous
//
#include <hip/hip_runtime.h>
#include <math.h>

#define Nn 8192
#define Cc 256
#define Dd 128
#define CAP 192   // max row degree: mean ~83, max over 8192 rows ~125

typedef float fx4 __attribute__((ext_vector_type(4)));

// ---------------- h = x @ W^T ----------------
__global__ __launch_bounds__(256) void h_kernel(const float* __restrict__ x,
                                                const float* __restrict__ W,
                                                float* __restrict__ h) {
  __shared__ float xs[32 * Cc];  // 32 KB
  const int tid = threadIdx.x;
  const int row0 = blockIdx.x * 32;
  const float4* xg4 = (const float4*)(x + (size_t)row0 * Cc);
  float4* xs4 = (float4*)xs;
#pragma unroll
  for (int k = 0; k < 8; ++k) xs4[tid + k * 256] = xg4[tid + k * 256];
  __syncthreads();

  const int d = tid & 127;
  const int g = tid >> 7;
  const float4* w4 = (const float4*)(W + (size_t)d * Cc);
  const float4* xt = (const float4*)(xs + g * 16 * Cc);

  float acc[16];
#pragma unroll
  for (int r = 0; r < 16; ++r) acc[r] = 0.f;

#pragma unroll 2
  for (int c4 = 0; c4 < Cc / 4; ++c4) {
    const float4 w = w4[c4];
#pragma unroll
    for (int r = 0; r < 16; ++r) {
      const float4 a = xt[r * (Cc / 4) + c4];  // wave-uniform LDS broadcast
      acc[r] += a.x * w.x + a.y * w.y + a.z * w.z + a.w * w.w;
    }
  }
  const int rbase = row0 + g * 16;
#pragma unroll
  for (int r = 0; r < 16; ++r) {
    h[(size_t)(rbase + r) * Dd + d] = acc[r];
  }
}

// ---------------- pure-stream scan: graph row -> compacted edge list -------
// One wave per row. No atomics, no barriers. Ballot+popcll compaction into a
// per-wave LDS slice; one coalesced write of the edge list at the end.
__global__ __launch_bounds__(256) void scan_kernel(const float* __restrict__ graph,
                                                   int* __restrict__ counts,
                                                   int* __restrict__ edges) {
  __shared__ int idxs[4][CAP];
  const int wv   = threadIdx.x >> 6;
  const int lane = threadIdx.x & 63;
  const int i = blockIdx.x * 4 + wv;
  int* idx = idxs[wv];

  const fx4* row = (const fx4*)(graph + (size_t)i * Nn);
  const unsigned long long lmask = (1ull << lane) - 1ull;
  int cnt = 0;  // wave-uniform (SGPR)

#pragma unroll
  for (int c = 0; c < 4; ++c) {
    fx4 v[8];
#pragma unroll
    for (int t = 0; t < 8; ++t)
      v[t] = __builtin_nontemporal_load(&row[(c * 8 + t) * 64 + lane]);  // 8 KB in flight
#pragma unroll
    for (int t = 0; t < 8; ++t) {
      const int col = 4 * ((c * 8 + t) * 64 + lane);
      {
        const unsigned long long mk = __ballot(v[t].x != 0.f);
        const int p = cnt + __popcll(mk & lmask);
        if (v[t].x != 0.f && p < CAP) idx[p] = col + 0;
        cnt += __popcll(mk);
      }
      {
        const unsigned long long mk = __ballot(v[t].y != 0.f);
        const int p = cnt + __popcll(mk & lmask);
        if (v[t].y != 0.f && p < CAP) idx[p] = col + 1;
        cnt += __popcll(mk);
      }
      {
        const unsigned long long mk = __ballot(v[t].z != 0.f);
        const int p = cnt + __popcll(mk & lmask);
        if (v[t].z != 0.f && p < CAP) idx[p] = col + 2;
        cnt += __popcll(mk);
      }
      {
        const unsigned long long mk = __ballot(v[t].w != 0.f);
        const int p = cnt + __popcll(mk & lmask);
        if (v[t].w != 0.f && p < CAP) idx[p] = col + 3;
        cnt += __popcll(mk);
      }
    }
  }
  const int m = min(cnt, CAP);
  for (int e = lane; e < m; e += 64) edges[(size_t)i * CAP + e] = idx[e];
  if (lane == 0) counts[i] = m;
}

// ---------------- sparse masked softmax + aggregate ------------------------
// One wave per row, 4 waves/block, no barriers (per-wave LDS slices).
__global__ __launch_bounds__(256) void attn_kernel(const int* __restrict__ counts,
                                                   const int* __restrict__ edges,
                                                   const float* __restrict__ h,
                                                   const float* __restrict__ bias,
                                                   float* __restrict__ out) {
  __shared__ int   idxs[4][CAP];
  __shared__ float scs[4][CAP];
  __shared__ float his[4][Dd];
  const int wv   = threadIdx.x >> 6;
  const int lane = threadIdx.x & 63;
  const int i = blockIdx.x * 4 + wv;
  int*   idx = idxs[wv];
  float* sc  = scs[wv];
  float* hi  = his[wv];

  const int m = counts[i];
  *(float2*)(hi + lane * 2) = *(const float2*)(h + (size_t)i * Dd + lane * 2);

  // edge list -> LDS (coalesced; wave-synchronous, each lane re-reads only
  // entries it wrote in the scores loop)
  const int* erow = edges + (size_t)i * CAP;
  for (int e = lane; e < m; e += 64) idx[e] = erow[e];

  // scores: one edge per lane (h rows are L2/L3-hot, no graph stream now)
  const float4* h4 = (const float4*)hi;
  for (int e = lane; e < m; e += 64) {
    const int j = idx[e];
    const float4* hj = (const float4*)(h + (size_t)j * Dd);
    float s0 = 0.f, s1 = 0.f, s2 = 0.f, s3 = 0.f;
#pragma unroll
    for (int k = 0; k < Dd / 4; ++k) {
      const float4 a = h4[k];
      const float4 b = hj[k];
      s0 += a.x * b.x; s1 += a.y * b.y; s2 += a.z * b.z; s3 += a.w * b.w;
    }
    sc[e] = (s0 + s1) + (s2 + s3);
  }

  // wave softmax over unmasked (s != 0) scores
  float lmax = -INFINITY;
  for (int e = lane; e < m; e += 64) {
    const float s = sc[e];
    if (s != 0.f) lmax = fmaxf(lmax, s);
  }
#pragma unroll
  for (int off = 32; off > 0; off >>= 1) lmax = fmaxf(lmax, __shfl_xor(lmax, off));

  float lsum = 0.f;
  for (int e = lane; e < m; e += 64) {
    const float s = sc[e];
    const float p = (s != 0.f) ? __expf(s - lmax) : 0.f;
    sc[e] = p;
    lsum += p;
  }
#pragma unroll
  for (int off = 32; off > 0; off >>= 1) lsum += __shfl_xor(lsum, off);
  const float inv = 1.f / lsum;

  // aggregate: lane owns d = lane*2 .. +1 (coalesced 512B row reads)
  float accx = 0.f, accy = 0.f;
#pragma unroll 8
  for (int e = 0; e < m; ++e) {
    const float p = sc[e];        // uniform LDS broadcast
    const int j = idx[e];
    const float2 hv = *(const float2*)(h + (size_t)j * Dd + lane * 2);
    accx += p * hv.x;
    accy += p * hv.y;
  }
  const float2 bv = *(const float2*)(bias + lane * 2);
  float2 o;
  o.x = accx * inv + bv.x;
  o.y = accy * inv + bv.y;
  *(float2*)(out + (size_t)i * Dd + lane * 2) = o;
}

extern "C" void kernel_launch(void* const* d_in, const int* in_sizes, int n_in,
                              void* d_out, int out_size, void* d_ws, size_t ws_size,
                              hipStream_t stream) {
  const float* x     = (const float*)d_in[0];  // [1,8192,256]
  const float* graph = (const float*)d_in[1];  // [8192,8192]
  const float* W     = (const float*)d_in[2];  // [128,256]
  const float* bias  = (const float*)d_in[3];  // [128]
  float* out = (float*)d_out;                  // [1,8192,128]

  // ws layout: h (4 MB) | counts (32 KB) | edges (6 MB)
  float* h      = (float*)d_ws;
  int*   counts = (int*)((char*)d_ws + (size_t)Nn * Dd * 4);
  int*   edges  = counts + Nn;

  h_kernel<<<Nn / 32, 256, 0, stream>>>(x, W, h);
  scan_kernel<<<Nn / 4, 256, 0, stream>>>(graph, counts, edges);
  attn_kernel<<<Nn / 4, 256, 0, stream>>>(counts, edges, h, bias, out);
}